// Round 4
// baseline (478.159 us; speedup 1.0000x reference)
//
#include <hip/hip_runtime.h>

// ---------------------------------------------------------------------------
// ActorCriticNetMixtureExpert: B=16384, D=512, H=512, HV=256, A=32, E=8, HW=512
// Outputs: actions [8,16384,32] f32 | v [16384,1] f32 | w [16384,8] f32
// ---------------------------------------------------------------------------

typedef float   f32x4 __attribute__((ext_vector_type(4)));
typedef _Float16 f16;
typedef _Float16 f16x4 __attribute__((ext_vector_type(4)));
typedef _Float16 f16x8 __attribute__((ext_vector_type(8)));

typedef __attribute__((address_space(1))) unsigned int gas_u32;
typedef __attribute__((address_space(3))) unsigned int las_u32;

__device__ __forceinline__ void gl_lds16(const void* g, void* l) {
  __builtin_amdgcn_global_load_lds((gas_u32*)g, (las_u32*)l, 16, 0, 0);
}

// bijective XCD-chunked swizzle (m204)
__device__ __forceinline__ int xcd_swz(int b, int G) {
  int q = G >> 3, r = G & 7;
  int x = b & 7, y = b >> 3;
  return (x < r ? x * (q + 1) : r * (q + 1) + (x - r) * q) + y;
}

// ---------------------------------------------------------------------------
// 256x256 / 8-wave / BK=64 pipelined GEMM (relu -> f16 out), expert-concat N.
// Ring of 8 x 16KB half-tile LDS slots; per K-tile 4 quadrant phases; counted
// vmcnt(4) once per tile; raw s_barrier (2/phase); setprio around MFMA.
// A-half h = rows {h*64..h*64+63} U {128+h*64..+63} (so ALL waves finish a
// half at the same phase). B-half h = n-rows {wc*64+h*32..+31} per wave.
// Stage order at tile t: q0:A1(t+1) q1:B1(t+1) q2:A0(t+2) q3:B0(t+2).
// ---------------------------------------------------------------------------
__global__ __launch_bounds__(512, 2) void gemm8_kernel(
    const f16* __restrict__ A, const f16* __restrict__ BT,
    const float* __restrict__ bias, f16* __restrict__ C,
    const int K, const long long sAe, const long long sCe,
    const int mT, const int nInner, const int eShift)
{
  __shared__ __align__(1024) char sm[131072];  // 8 slots x 16KB

  const int tid = threadIdx.x;
  const int lane = tid & 63;
  const int wid = tid >> 6;
  const int wr = wid >> 2, wc = wid & 3;
  const int kl = (lane >> 4) << 4;

  const int L = xcd_swz(blockIdx.x, gridDim.x);
  const int nIn = L % nInner;
  const int m = (L / nInner) % mT;
  const int eo = L / (nInner * mT);
  const int Nreal = 1 << eShift;
  const int nv0 = (eo * nInner + nIn) << 8;
  const int e = nv0 >> eShift;
  const int col0 = nv0 & (Nreal - 1);
  const int m0 = m << 8;

  const f16* Ab = A + (size_t)sAe * e + (size_t)m0 * K;
  const f16* Bb = BT + (size_t)nv0 * K;
  const int nt = K >> 6;

  f32x4 acc[8][4] = {};

// stage one 16KB half-tile: 2 x gl_lds16 per thread. sp_: slot parity (0/1),
// ta_: K-tile index for the global address, h_: half.
#define STAGE_A(sp_, ta_, h_) { \
  char* dst = sm + (((sp_) * 4 + (h_)) << 14); \
  _Pragma("unroll") for (int i = 0; i < 2; ++i) { \
    int u = tid + (i << 9); int p = u >> 3; \
    const char* src = (const char*)(Ab + (size_t)(((p >> 6) << 7) + ((h_) << 6) + (p & 63)) * K) \
                      + ((size_t)(ta_) << 7) + (((u & 7) << 4) ^ ((p & 7) << 4)); \
    gl_lds16(src, dst + u * 16); } }

#define STAGE_B(sp_, ta_, h_) { \
  char* dst = sm + (((sp_) * 4 + 2 + (h_)) << 14); \
  _Pragma("unroll") for (int i = 0; i < 2; ++i) { \
    int u = tid + (i << 9); int p = u >> 3; \
    const char* src = (const char*)(Bb + (size_t)(((p >> 5) << 6) + ((h_) << 5) + (p & 31)) * K) \
                      + ((size_t)(ta_) << 7) + (((u & 7) << 4) ^ ((p & 7) << 4)); \
    gl_lds16(src, dst + u * 16); } }

#define VMCNT4 { asm volatile("s_waitcnt vmcnt(4)" ::: "memory"); \
                 __builtin_amdgcn_sched_barrier(0); }

#define PHASE(t_, mh_, nh_, STAGE_CODE) { \
  const char* sA = sm + ((((t_) & 1) * 4 + (mh_)) << 14); \
  const char* sB = sm + ((((t_) & 1) * 4 + 2 + (nh_)) << 14); \
  f16x8 af[4][2], bf[2][2]; \
  _Pragma("unroll") for (int fm = 0; fm < 4; ++fm) { \
    int p = (wr << 6) + (fm << 4) + (lane & 15); int sw = (p & 7) << 4; \
    af[fm][0] = *(const f16x8*)(sA + p * 128 + (kl ^ sw)); \
    af[fm][1] = *(const f16x8*)(sA + p * 128 + ((64 + kl) ^ sw)); } \
  _Pragma("unroll") for (int fn = 0; fn < 2; ++fn) { \
    int p = (wc << 5) + (fn << 4) + (lane & 15); int sw = (p & 7) << 4; \
    bf[fn][0] = *(const f16x8*)(sB + p * 128 + (kl ^ sw)); \
    bf[fn][1] = *(const f16x8*)(sB + p * 128 + ((64 + kl) ^ sw)); } \
  STAGE_CODE; \
  __builtin_amdgcn_s_barrier(); \
  __builtin_amdgcn_s_setprio(1); \
  _Pragma("unroll") for (int fm = 0; fm < 4; ++fm) \
  _Pragma("unroll") for (int fn = 0; fn < 2; ++fn) { \
    acc[(mh_) * 4 + fm][(nh_) * 2 + fn] = __builtin_amdgcn_mfma_f32_16x16x32_f16( \
        bf[fn][0], af[fm][0], acc[(mh_) * 4 + fm][(nh_) * 2 + fn], 0, 0, 0); \
    acc[(mh_) * 4 + fm][(nh_) * 2 + fn] = __builtin_amdgcn_mfma_f32_16x16x32_f16( \
        bf[fn][1], af[fm][1], acc[(mh_) * 4 + fm][(nh_) * 2 + fn], 0, 0, 0); } \
  __builtin_amdgcn_s_setprio(0); \
  __builtin_amdgcn_s_barrier(); }

  // prologue: tile0 complete + A0/B0 of tile1 in flight
  STAGE_A(0, 0, 0); STAGE_B(0, 0, 0); STAGE_A(0, 0, 1); STAGE_B(0, 0, 1);
  STAGE_A(1, 1, 0); STAGE_B(1, 1, 0);
  VMCNT4;
  __builtin_amdgcn_s_barrier();

  for (int t = 0; t < nt; ++t) {
    const int tp1 = (t + 1 < nt) ? t + 1 : t;
    const int tp2 = (t + 2 < nt) ? t + 2 : nt - 1;
    const int sp1 = (t + 1) & 1, sp0 = t & 1;
    PHASE(t, 0, 0, STAGE_A(sp1, tp1, 1));
    PHASE(t, 0, 1, STAGE_B(sp1, tp1, 1));
    PHASE(t, 1, 0, STAGE_A(sp0, tp2, 0));
    PHASE(t, 1, 1, STAGE_B(sp0, tp2, 0); VMCNT4);
  }
  asm volatile("s_waitcnt vmcnt(0)" ::: "memory");

#undef PHASE
#undef VMCNT4
#undef STAGE_A
#undef STAGE_B

  // epilogue: row = m0 + wr*128 + fa*16 + (lane&15); col = wc*64 + fb*16 + (lane>>4)*4
  const int rbase = m0 + (wr << 7) + (lane & 15);
  const int cb = (wc << 6) + ((lane >> 4) << 2);
  #pragma unroll
  for (int fa = 0; fa < 8; ++fa) {
    const int row = rbase + fa * 16;
    #pragma unroll
    for (int fb = 0; fb < 4; ++fb) {
      const int bcol = cb + fb * 16;
      f32x4 v = acc[fa][fb];
      f32x4 bb = *(const f32x4*)(bias + nv0 + bcol);
      f16x4 h;
      #pragma unroll
      for (int r = 0; r < 4; ++r) h[r] = (f16)fmaxf(v[r] + bb[r], 0.0f);
      *(f16x4*)(C + (size_t)sCe * e + (size_t)row * Nreal + col0 + bcol) = h;
    }
  }
}

// ---------------------------------------------------------------------------
// small GEMM for the mu layer (N=32): 128x32 tile, BK=64  (proven round-3)
// EPI 1: tanh -> f32 out
// ---------------------------------------------------------------------------
template<int BM, int BN, int WM, int WN, int EPI>
__global__ __launch_bounds__(256, 2) void gemm2_kernel(
    const f16* __restrict__ A, const f16* __restrict__ BT,
    const float* __restrict__ bias, void* __restrict__ Cv,
    const int K, const long long sAe, const long long sCe,
    const int mT, const int nInner, const int eShift)
{
  constexpr int FM = WM / 16, FN = WN / 16;
  constexpr int WAVES_N = BN / WN;
  __shared__ __align__(16) char sm[(BM + BN) * 128];
  char* Ash = sm;
  char* Bsh = sm + BM * 128;

  const int tid = threadIdx.x;
  const int lane = tid & 63;
  const int wid = tid >> 6;

  const int L = xcd_swz(blockIdx.x, gridDim.x);
  const int nIn = L % nInner;
  const int m = (L / nInner) % mT;
  const int eo = L / (nInner * mT);
  const int Nreal = 1 << eShift;
  const int nv0 = (eo * nInner + nIn) * BN;
  const int e = nv0 >> eShift;
  const int col0 = nv0 & (Nreal - 1);
  const int m0 = m * BM;

  const f16* Ab = A + (size_t)sAe * e + (size_t)m0 * K;
  const f16* Bb = BT + (size_t)nv0 * K;
  const int wr = wid / WAVES_N, wc = wid % WAVES_N;

  f32x4 acc[FM][FN] = {};

  const int ksteps = K >> 6;
  for (int kt = 0; kt < ksteps; ++kt) {
    __syncthreads();
    const f16* Ak = Ab + (kt << 6);
    const f16* Bk = Bb + (kt << 6);
    for (int u = tid; u < BM * 8; u += 256) {
      int row = u >> 3;
      int kb = ((u & 7) << 4) ^ ((row & 7) << 4);
      gl_lds16(Ak + (size_t)row * K + (kb >> 1), Ash + u * 16);
    }
    for (int u = tid; u < BN * 8; u += 256) {
      int row = u >> 3;
      int kb = ((u & 7) << 4) ^ ((row & 7) << 4);
      gl_lds16(Bk + (size_t)row * K + (kb >> 1), Bsh + u * 16);
    }
    __syncthreads();

    f16x8 af[FM][2], bf[FN][2];
    const int kl = (lane >> 4) << 4;
    #pragma unroll
    for (int fm = 0; fm < FM; ++fm) {
      int row = wr * WM + fm * 16 + (lane & 15);
      int sw = (row & 7) << 4;
      af[fm][0] = *(const f16x8*)(Ash + row * 128 + (kl ^ sw));
      af[fm][1] = *(const f16x8*)(Ash + row * 128 + ((64 + kl) ^ sw));
    }
    #pragma unroll
    for (int fn = 0; fn < FN; ++fn) {
      int row = wc * WN + fn * 16 + (lane & 15);
      int sw = (row & 7) << 4;
      bf[fn][0] = *(const f16x8*)(Bsh + row * 128 + (kl ^ sw));
      bf[fn][1] = *(const f16x8*)(Bsh + row * 128 + ((64 + kl) ^ sw));
    }
    #pragma unroll
    for (int fm = 0; fm < FM; ++fm)
      #pragma unroll
      for (int fn = 0; fn < FN; ++fn) {
        acc[fm][fn] = __builtin_amdgcn_mfma_f32_16x16x32_f16(
            bf[fn][0], af[fm][0], acc[fm][fn], 0, 0, 0);
        acc[fm][fn] = __builtin_amdgcn_mfma_f32_16x16x32_f16(
            bf[fn][1], af[fm][1], acc[fm][fn], 0, 0, 0);
      }
  }

  const int rbase = m0 + wr * WM + (lane & 15);
  const int cb = wc * WN + ((lane >> 4) << 2);
  #pragma unroll
  for (int fm = 0; fm < FM; ++fm) {
    const int row = rbase + fm * 16;
    #pragma unroll
    for (int fn = 0; fn < FN; ++fn) {
      const int bcol = cb + fn * 16;
      f32x4 v = acc[fm][fn];
      f32x4 bb = *(const f32x4*)(bias + nv0 + bcol);
      if constexpr (EPI == 0) {
        f16x4 h;
        #pragma unroll
        for (int r = 0; r < 4; ++r) h[r] = (f16)fmaxf(v[r] + bb[r], 0.0f);
        *(f16x4*)((f16*)Cv + (size_t)sCe * e + (size_t)row * Nreal + col0 + bcol) = h;
      } else {
        f32x4 o;
        #pragma unroll
        for (int r = 0; r < 4; ++r) o[r] = tanhf(v[r] + bb[r]);
        *(f32x4*)((float*)Cv + (size_t)sCe * e + (size_t)row * Nreal + col0 + bcol) = o;
      }
    }
  }
}

// ---------------------------------------------------------------------------
// High-precision gating GEMM via fp16x2 split (proven round-2/3)
// ---------------------------------------------------------------------------
__device__ __forceinline__ int swz32(int row) { return ((row >> 1) & 3) << 4; }

__global__ __launch_bounds__(256, 2) void gemm_gate_kernel(
    const f16* __restrict__ Ahi, const f16* __restrict__ Alo,
    const f16* __restrict__ Bhi, const f16* __restrict__ Blo,
    const float* __restrict__ bias,
    f16* __restrict__ Chi, f16* __restrict__ Clo, float* __restrict__ C32,
    const int M, const int N, const int K, const int mode)
{
  constexpr int FM = 4, FN = 4, WAVES_N = 2;
  __shared__ __align__(16) char sm[4 * 128 * 64];
  char* AH = sm;
  char* AL = sm + 8192;
  char* BH = sm + 16384;
  char* BL = sm + 24576;

  const int tid = threadIdx.x;
  const int lane = tid & 63;
  const int wid = tid >> 6;
  const int L = xcd_swz(blockIdx.x, gridDim.x);
  const int ntn = N / 128;
  const int m0 = (L / ntn) * 128;
  const int n0 = (L % ntn) * 128;
  const int wr = wid / WAVES_N, wc = wid % WAVES_N;

  f32x4 a1[FM][FN] = {};
  f32x4 a2[FM][FN] = {};

  const int ksteps = K >> 5;
  for (int kt = 0; kt < ksteps; ++kt) {
    __syncthreads();
    const size_t ko = (size_t)(kt << 5);
    for (int u = tid; u < 512; u += 256) {
      int row = u >> 2;
      int kb = ((u & 3) << 4) ^ swz32(row);
      size_t ga = (size_t)(m0 + row) * K + ko + (kb >> 1);
      size_t gb = (size_t)(n0 + row) * K + ko + (kb >> 1);
      gl_lds16(Ahi + ga, AH + u * 16);
      gl_lds16(Alo + ga, AL + u * 16);
      gl_lds16(Bhi + gb, BH + u * 16);
      gl_lds16(Blo + gb, BL + u * 16);
    }
    __syncthreads();

    f16x8 ah[FM], al[FM], bh[FN], bl[FN];
    const int kl = (lane >> 4) << 4;
    #pragma unroll
    for (int fm = 0; fm < FM; ++fm) {
      int row = wr * 64 + fm * 16 + (lane & 15);
      int o = row * 64 + (kl ^ swz32(row));
      ah[fm] = *(const f16x8*)(AH + o);
      al[fm] = *(const f16x8*)(AL + o);
    }
    #pragma unroll
    for (int fn = 0; fn < FN; ++fn) {
      int row = wc * 64 + fn * 16 + (lane & 15);
      int o = row * 64 + (kl ^ swz32(row));
      bh[fn] = *(const f16x8*)(BH + o);
      bl[fn] = *(const f16x8*)(BL + o);
    }
    #pragma unroll
    for (int fm = 0; fm < FM; ++fm)
      #pragma unroll
      for (int fn = 0; fn < FN; ++fn) {
        a1[fm][fn] = __builtin_amdgcn_mfma_f32_16x16x32_f16(bh[fn], ah[fm], a1[fm][fn], 0, 0, 0);
        a2[fm][fn] = __builtin_amdgcn_mfma_f32_16x16x32_f16(bh[fn], al[fm], a2[fm][fn], 0, 0, 0);
        a2[fm][fn] = __builtin_amdgcn_mfma_f32_16x16x32_f16(bl[fn], ah[fm], a2[fm][fn], 0, 0, 0);
      }
  }

  const int rbase = m0 + wr * 64 + (lane & 15);
  const int cbase = n0 + wc * 64 + ((lane >> 4) << 2);
  #pragma unroll
  for (int fm = 0; fm < FM; ++fm) {
    const int row = rbase + fm * 16;
    #pragma unroll
    for (int fn = 0; fn < FN; ++fn) {
      const int col = cbase + fn * 16;
      f32x4 bb = *(const f32x4*)(bias + col);
      if (mode == 0) {
        f16x4 h, l;
        #pragma unroll
        for (int r = 0; r < 4; ++r) {
          float u = fmaxf(a1[fm][fn][r] + a2[fm][fn][r] * 9.765625e-4f + bb[r], 0.0f);
          f16 hh = (f16)u;
          h[r] = hh;
          l[r] = (f16)((u - (float)hh) * 1024.0f);
        }
        *(f16x4*)(Chi + (size_t)row * N + col) = h;
        *(f16x4*)(Clo + (size_t)row * N + col) = l;
      } else {
        f32x4 o;
        #pragma unroll
        for (int r = 0; r < 4; ++r)
          o[r] = fmaxf(a1[fm][fn][r] + a2[fm][fn][r] * 9.765625e-4f + bb[r], 0.0f);
        *(f32x4*)(C32 + (size_t)row * N + col) = o;
      }
    }
  }
}

// ---------------------------------------------------------------------------
// Fused prep: cvt x -> hi/lo  +  all weight transposes (one dispatch)
// ---------------------------------------------------------------------------
__global__ __launch_bounds__(256) void prep_kernel(
    const float* __restrict__ x, f16* __restrict__ xhi, f16* __restrict__ xlo,
    const float* __restrict__ Wp0, f16* __restrict__ Wp0T,
    const float* __restrict__ Wp1, f16* __restrict__ Wp1T,
    const float* __restrict__ Wmu, f16* __restrict__ WmuT,
    const float* __restrict__ Wv0, f16* __restrict__ Wv0T,
    const float* __restrict__ Wv1, f16* __restrict__ Wv1T,
    const float* __restrict__ Ww0, f16* __restrict__ Ww0Thi, f16* __restrict__ Ww0Tlo,
    const float* __restrict__ Ww1, f16* __restrict__ Ww1Thi, f16* __restrict__ Ww1Tlo)
{
  __shared__ float t[32][33];
  const int tid = threadIdx.x;
  int b = blockIdx.x;
  if (b < 8192) {
    const size_t i = ((size_t)b * 256 + tid) * 4;
    f32x4 v = *(const f32x4*)(x + i);
    f16x4 h, l;
    #pragma unroll
    for (int j = 0; j < 4; ++j) {
      f16 hh = (f16)v[j];
      h[j] = hh;
      l[j] = (f16)((v[j] - (float)hh) * 1024.0f);
    }
    *(f16x4*)(xhi + i) = h;
    *(f16x4*)(xlo + i) = l;
    return;
  }
  b -= 8192;
  const float* W;
  f16* T;
  f16* T2 = nullptr;
  int K, N;
  if (b < 2048)               { W = Wp0; T = Wp0T; K = 512; N = 512; }
  else if ((b -= 2048) < 2048){ W = Wp1; T = Wp1T; K = 512; N = 512; }
  else if ((b -= 2048) < 128) { W = Wmu; T = WmuT; K = 512; N = 32; }
  else if ((b -= 128) < 1024) { W = Wv0; T = Wv0T; K = 512; N = 256; }
  else if ((b -= 1024) < 512) { W = Wv1; T = Wv1T; K = 256; N = 256; }
  else if ((b -= 512) < 256)  { W = Ww0; T = Ww0Thi; T2 = Ww0Tlo; K = 512; N = 512; }
  else { b -= 256;              W = Ww1; T = Ww1Thi; T2 = Ww1Tlo; K = 512; N = 512; }

  const int kT = K >> 5, nT = N >> 5;
  const int e = b / (kT * nT);
  const int rem = b % (kT * nT);
  const int k0 = (rem % kT) << 5;
  const int n0 = (rem / kT) << 5;
  const int tx = tid & 31, ty = tid >> 5;
  const float* Wp = W + (size_t)e * K * N;
  #pragma unroll
  for (int i = 0; i < 4; ++i)
    t[ty + i * 8][tx] = Wp[(size_t)(k0 + ty + i * 8) * N + n0 + tx];
  __syncthreads();
  f16* Op = T + (size_t)e * K * N;
  #pragma unroll
  for (int i = 0; i < 4; ++i) {
    const int n = n0 + ty + i * 8, k = k0 + tx;
    float v = t[tx][ty + i * 8];
    f16 hh = (f16)v;
    Op[(size_t)n * K + k] = hh;
    if (T2) T2[(size_t)n * K + k] = (f16)((v - (float)hh) * 1024.0f);
  }
}

// ---------------------------------------------------------------------------
// Per-expert value head
// ---------------------------------------------------------------------------
__global__ __launch_bounds__(256) void values_kernel(
    const f16* __restrict__ G2, const float* __restrict__ Wv,
    const float* __restrict__ bv, float* __restrict__ values, const int e0)
{
  const int tid = threadIdx.x, lane = tid & 63, wid = tid >> 6;
  const int gi = blockIdx.x * 4 + wid;
  const int el = gi >> 14;
  const int b = gi & 16383;
  const int eg = e0 + el;
  const f16* g = G2 + (((size_t)el << 14) + b) * 256 + (lane << 2);
  f16x4 gv = *(const f16x4*)g;
  const float* wv = Wv + ((size_t)eg << 8) + (lane << 2);
  float a = (float)gv[0] * wv[0] + (float)gv[1] * wv[1] +
            (float)gv[2] * wv[2] + (float)gv[3] * wv[3];
  #pragma unroll
  for (int off = 32; off >= 1; off >>= 1) a += __shfl_xor(a, off);
  if (lane == 0) values[((size_t)eg << 14) + b] = a + bv[eg];
}

// ---------------------------------------------------------------------------
// Threefry-2x32-20, key = (0, 42)
// ---------------------------------------------------------------------------
__device__ __forceinline__ void threefry_0_42(unsigned x0, unsigned x1,
                                              unsigned& o0, unsigned& o1)
{
  const unsigned ks0 = 0u, ks1 = 42u, ks2 = 0x1BD11BDAu ^ 42u;
  x0 += ks0; x1 += ks1;
#define TF_R(r) { x0 += x1; x1 = (x1 << r) | (x1 >> (32 - r)); x1 ^= x0; }
  TF_R(13) TF_R(15) TF_R(26) TF_R(6)  x0 += ks1; x1 += ks2 + 1u;
  TF_R(17) TF_R(29) TF_R(16) TF_R(24) x0 += ks2; x1 += ks0 + 2u;
  TF_R(13) TF_R(15) TF_R(26) TF_R(6)  x0 += ks0; x1 += ks1 + 3u;
  TF_R(17) TF_R(29) TF_R(16) TF_R(24) x0 += ks1; x1 += ks2 + 4u;
  TF_R(13) TF_R(15) TF_R(26) TF_R(6)  x0 += ks2; x1 += ks0 + 5u;
#undef TF_R
  o0 = x0; o1 = x1;
}

// ---------------------------------------------------------------------------
// Gating tail (softmax + partitionable-threefry categorical + gather)
// ---------------------------------------------------------------------------
__global__ __launch_bounds__(256) void gating_out_kernel(
    const float* __restrict__ U2, const float* __restrict__ Wwo,
    const float* __restrict__ bwo, const float* __restrict__ values,
    float* __restrict__ w_out, float* __restrict__ v_out)
{
  __shared__ float wl[4096];
  const int tid = threadIdx.x;
  for (int i = tid; i < 1024; i += 256)
    ((f32x4*)wl)[i] = ((const f32x4*)Wwo)[i];
  __syncthreads();
  const int lane = tid & 63, wid = tid >> 6;
  const int b = blockIdx.x * 4 + wid;

  const float* u = U2 + (size_t)b * 512 + lane * 8;
  f32x4 ua = *(const f32x4*)u;
  f32x4 ub = *(const f32x4*)(u + 4);
  float acc[8] = {};
  const float* wrow = wl + lane * 64;
  #pragma unroll
  for (int i = 0; i < 8; ++i) {
    float uv = (i < 4) ? ua[i] : ub[i - 4];
    #pragma unroll
    for (int ee = 0; ee < 8; ++ee) acc[ee] += uv * wrow[i * 8 + ee];
  }
  #pragma unroll
  for (int off = 32; off >= 1; off >>= 1)
    #pragma unroll
    for (int ee = 0; ee < 8; ++ee) acc[ee] += __shfl_xor(acc[ee], off);
  #pragma unroll
  for (int ee = 0; ee < 8; ++ee) acc[ee] += bwo[ee];

  float zmax = acc[0];
  #pragma unroll
  for (int ee = 1; ee < 8; ++ee) zmax = fmaxf(zmax, acc[ee]);
  float s = 0.0f;
  #pragma unroll
  for (int ee = 0; ee < 8; ++ee) s += expf(acc[ee] - zmax);

  float t0 = (lane & 1) ? acc[1] : acc[0];
  float t1 = (lane & 1) ? acc[3] : acc[2];
  float t2 = (lane & 1) ? acc[5] : acc[4];
  float t3 = (lane & 1) ? acc[7] : acc[6];
  float s0 = (lane & 2) ? t1 : t0;
  float s1 = (lane & 2) ? t3 : t2;
  float zown = (lane & 4) ? s1 : s0;

  if (lane < 8) w_out[(size_t)b * 8 + lane] = expf(zown - zmax) / s;

  unsigned idx = ((unsigned)b << 3) | (unsigned)(lane & 7);
  unsigned o0, o1;
  threefry_0_42(0u, idx, o0, o1);
  unsigned bits = o0 ^ o1;
  float f = __uint_as_float((bits >> 9) | 0x3F800000u) - 1.0f;
  f = fmaxf(f, 1.17549435e-38f);
  float g = -logf(-logf(f));
  float y = (lane < 8) ? (zown + g) : -3.0e38f;

  float best = __shfl(y, 0);
  int pi = 0;
  #pragma unroll
  for (int ee = 1; ee < 8; ++ee) {
    float ye = __shfl(y, ee);
    if (ye > best) { best = ye; pi = ee; }
  }
  if (lane == 0) v_out[b] = values[((size_t)pi << 14) + b];
}

// ---------------------------------------------------------------------------
// host launch
// ---------------------------------------------------------------------------
extern "C" void kernel_launch(void* const* d_in, const int* in_sizes, int n_in,
                              void* d_out, int out_size, void* d_ws, size_t ws_size,
                              hipStream_t stream) {
  (void)in_sizes; (void)n_in; (void)out_size;
  const float* x   = (const float*)d_in[0];
  const float* Wp0 = (const float*)d_in[1];
  const float* bp0 = (const float*)d_in[2];
  const float* Wp1 = (const float*)d_in[3];
  const float* bp1 = (const float*)d_in[4];
  const float* Wmu = (const float*)d_in[5];
  const float* bmu = (const float*)d_in[6];
  const float* Wv0 = (const float*)d_in[7];
  const float* bv0 = (const float*)d_in[8];
  const float* Wv1 = (const float*)d_in[9];
  const float* bv1 = (const float*)d_in[10];
  const float* Wv  = (const float*)d_in[11];
  const float* bv  = (const float*)d_in[12];
  const float* Ww0 = (const float*)d_in[13];
  const float* bw0 = (const float*)d_in[14];
  const float* Ww1 = (const float*)d_in[15];
  const float* bw1 = (const float*)d_in[16];
  const float* Wwo = (const float*)d_in[17];
  const float* bwo = (const float*)d_in[18];

  float* out_actions = (float*)d_out;
  float* out_v = out_actions + (size_t)8 * 16384 * 32;
  float* out_w = out_v + 16384;

  char* base = (char*)d_ws;
  size_t off = 0;
  auto alloc = [&](size_t bytes) -> char* {
    char* p = base + off;
    off = (off + bytes + 255) & ~(size_t)255;
    return p;
  };

  const size_t BD2 = (size_t)16384 * 512 * 2;
  const size_t BH2 = (size_t)16384 * 256 * 2;

  f16* x16    = (f16*)alloc(BD2);
  f16* xlo    = (f16*)alloc(BD2);
  f16* Wp0T   = (f16*)alloc((size_t)8 * 512 * 512 * 2);
  f16* Wp1T   = (f16*)alloc((size_t)8 * 512 * 512 * 2);
  f16* WmuT   = (f16*)alloc((size_t)8 * 32 * 512 * 2);
  f16* Wv0T   = (f16*)alloc((size_t)8 * 256 * 512 * 2);
  f16* Wv1T   = (f16*)alloc((size_t)8 * 256 * 256 * 2);
  f16* Ww0Thi = (f16*)alloc((size_t)512 * 512 * 2);
  f16* Ww0Tlo = (f16*)alloc((size_t)512 * 512 * 2);
  f16* Ww1Thi = (f16*)alloc((size_t)512 * 512 * 2);
  f16* Ww1Tlo = (f16*)alloc((size_t)512 * 512 * 2);
  float* valuesBuf = (float*)alloc((size_t)8 * 16384 * 4);

  size_t core = off;
  int eg = 8;
  while (eg > 1 && core + (size_t)2 * eg * BD2 > ws_size) eg >>= 1;
  const int eg_v = (2 * eg > 8) ? 8 : 2 * eg;

  f16 *BIG1, *BIG2, *U1hi, *U1lo;
  float* U2;
  if (eg >= 2) {
    BIG1 = (f16*)alloc((size_t)eg * BD2);
    BIG2 = (f16*)alloc((size_t)eg * BD2);
    U1hi = BIG1;
    U1lo = BIG1 + (size_t)16384 * 512;
    U2 = (float*)BIG2;
  } else {
    BIG1 = (f16*)alloc(BD2);
    BIG2 = (f16*)alloc(BD2);
    U1hi = (f16*)alloc(BD2);
    U1lo = (f16*)alloc(BD2);
    U2 = (float*)alloc((size_t)16384 * 512 * 4);
  }
  f16* VB1 = BIG1;
  f16* VB2 = (f16*)((char*)BIG1 + (size_t)eg_v * BH2);

  dim3 blk(256);
  dim3 blk8(512);
  const long long sBD = 16384LL * 512;
  const long long sBH = 16384LL * 256;

  // fused prep (cvt + all transposes)
  prep_kernel<<<14464, blk, 0, stream>>>(
      x, x16, xlo, Wp0, Wp0T, Wp1, Wp1T, Wmu, WmuT, Wv0, Wv0T, Wv1, Wv1T,
      Ww0, Ww0Thi, Ww0Tlo, Ww1, Ww1Thi, Ww1Tlo);

  // policy chain
  for (int e0 = 0; e0 < 8; e0 += eg) {
    gemm8_kernel<<<64 * 2 * eg, blk8, 0, stream>>>(
        x16, Wp0T + (size_t)e0 * 512 * 512, bp0 + e0 * 512, BIG1,
        512, 0, sBD, 64, 2 * eg, 9);
    gemm8_kernel<<<64 * 2 * eg, blk8, 0, stream>>>(
        BIG1, Wp1T + (size_t)e0 * 512 * 512, bp1 + e0 * 512, BIG2,
        512, sBD, sBD, 64, 2, 9);
    gemm2_kernel<128, 32, 32, 32, 1><<<128 * eg, blk, 0, stream>>>(
        BIG2, WmuT + (size_t)e0 * 32 * 512, bmu + e0 * 32,
        out_actions + (size_t)e0 * 16384 * 32,
        512, sBD, 16384LL * 32, 128, 1, 5);
  }

  // value chain
  for (int e0 = 0; e0 < 8; e0 += eg_v) {
    gemm8_kernel<<<64 * eg_v, blk8, 0, stream>>>(
        x16, Wv0T + (size_t)e0 * 256 * 512, bv0 + e0 * 256, VB1,
        512, 0, sBH, 64, eg_v, 8);
    gemm8_kernel<<<64 * eg_v, blk8, 0, stream>>>(
        VB1, Wv1T + (size_t)e0 * 256 * 256, bv1 + e0 * 256, VB2,
        256, sBH, sBH, 64, 1, 8);
    values_kernel<<<eg_v * 4096, blk, 0, stream>>>((const f16*)VB2, Wv, bv, valuesBuf, e0);
  }

  // gating network + tail
  gemm_gate_kernel<<<512, blk, 0, stream>>>(
      x16, xlo, Ww0Thi, Ww0Tlo, bw0, U1hi, U1lo, nullptr, 16384, 512, 512, 0);
  gemm_gate_kernel<<<512, blk, 0, stream>>>(
      U1hi, U1lo, Ww1Thi, Ww1Tlo, bw1, nullptr, nullptr, U2, 16384, 512, 512, 1);
  gating_out_kernel<<<4096, blk, 0, stream>>>(U2, Wwo, bwo, valuesBuf, out_w, out_v);
}